// Round 3
// baseline (495.756 us; speedup 1.0000x reference)
//
#include <hip/hip_runtime.h>
#include <hip/hip_bf16.h>
#include <stdint.h>

#define AS1 __attribute__((address_space(1)))
#define AS3 __attribute__((address_space(3)))

typedef __bf16 bf16x8 __attribute__((ext_vector_type(8)));
typedef __bf16 bf16x4 __attribute__((ext_vector_type(4)));
typedef float  f32x4  __attribute__((ext_vector_type(4)));

static constexpr int kL   = 8192;
static constexpr int kD   = 1024;
static constexpr int kM   = 2 * kL;         // 16384 token rows
static constexpr int kNCH = 16;             // KV k-split chunks over L
static constexpr int kSCH = kL / kNCH;      // 512 s-rows per chunk

__device__ __forceinline__ void async_cp16(__bf16* lds, const __bf16* g) {
    __builtin_amdgcn_global_load_lds((AS1 uint32_t*)g, (AS3 uint32_t*)lds, 16, 0, 0);
}

__device__ __forceinline__ float elu1f(float x) {
    return x > 0.0f ? x + 1.0f : __expf(x);
}

template <int M0>
__device__ __forceinline__ void mfma16(f32x4 (&acc)[8][4], const bf16x8 (&af)[4],
                                       const bf16x8 (&bq)[4]) {
#pragma unroll
    for (int i = 0; i < 4; ++i)
#pragma unroll
        for (int n = 0; n < 4; ++n)
            acc[M0 + i][n] = __builtin_amdgcn_mfma_f32_16x16x32_bf16(af[i], bq[n], acc[M0 + i][n], 0, 0, 0);
}

// ---------------------------------------------------------------------------
// 256x256 8-phase GEMM (T2+T3+T4+T5). C = A @ Bt^T.
// R9: race-free staging — during tile t, stage ONLY tile t+1 (one half-tile
// per phase, always into buffer (t+1)&1 != current). vmcnt(4) at end of ph1
// (guards this tile's kh1) and end of ph3 (guards next tile's kh0); tail uses
// vmcnt(0). Issue-to-wait lead = 3+ phases (m201 depth).
// EPI: 0 = plain, 1 = relu, 2 = Wq-epilogue (featG=elu rowmajor + qT + fT).
// ---------------------------------------------------------------------------
template <int EPI>
__global__ __launch_bounds__(512, 2) void gemm256(const __bf16* __restrict__ A,
                                                  const __bf16* __restrict__ Bt,
                                                  __bf16* __restrict__ C,
                                                  __bf16* __restrict__ qTp,
                                                  __bf16* __restrict__ fTp,
                                                  int M, int N, int K) {
    __shared__ __bf16 As[32768];
    __shared__ __bf16 Bs[32768];
    const int tid  = threadIdx.x;
    const int w    = tid >> 6;
    const int l    = tid & 63;
    const int quad = l >> 4;
    const int l16  = l & 15;
    const int wm   = w >> 2;               // 0..1
    const int wn   = w & 3;                // 0..3
    const int row0 = blockIdx.x * 256;
    const int col0 = blockIdx.y * 256;

    const int srow = l >> 2;               // 0..15
    const int sc   = ((l & 3) - (srow >> 1)) & 3;
    const __bf16* Ag0 = A  + (size_t)(row0 + w * 32 + srow) * K + sc * 8;
    const __bf16* Bg0 = Bt + (size_t)(col0 + w * 32 + srow) * K + sc * 8;
    const size_t r16K = (size_t)16 * K;
    const int NT = K >> 6;

    const int fpos = ((quad + (l16 >> 1)) & 3) * 8;
    const int arow = wm * 4096 + l16 * 32 + fpos;
    const int brow = wn * 2048 + l16 * 32 + fpos;

    f32x4 acc[8][4] = {};

    // half-tile stage: hh 0=A-kh0 1=B-kh0 2=A-kh1 3=B-kh1
    auto stage_h = [&](int ts, int hh) {
        if (ts >= NT) return;
        const int off = (ts & 1) * 16384 + (hh >> 1) * 8192 + w * 1024;
        const int ko  = ts * 64 + (hh >> 1) * 32;
        if ((hh & 1) == 0) {
            async_cp16(&As[off], Ag0 + ko);
            async_cp16(&As[off + 512], Ag0 + ko + r16K);
        } else {
            async_cp16(&Bs[off], Bg0 + ko);
            async_cp16(&Bs[off + 512], Bg0 + ko + r16K);
        }
    };

    // prologue: tile0 fully; kh0 landed before ph0
    stage_h(0, 0); stage_h(0, 1); stage_h(0, 2); stage_h(0, 3);
    asm volatile("s_waitcnt vmcnt(4)" ::: "memory");
    __builtin_amdgcn_s_barrier();

    for (int t = 0; t < NT; ++t) {
        const int bo = (t & 1) * 16384;
        bf16x8 af[4], bq[4];

        // ---- phase 0: kh0, m-half 0
#pragma unroll
        for (int i = 0; i < 4; ++i) af[i] = *(const bf16x8*)&As[bo + arow + i * 512];
#pragma unroll
        for (int n = 0; n < 4; ++n) bq[n] = *(const bf16x8*)&Bs[bo + brow + n * 512];
        stage_h(t + 1, 0);
        __builtin_amdgcn_s_barrier();
        asm volatile("s_waitcnt lgkmcnt(0)" ::: "memory");
        __builtin_amdgcn_sched_barrier(0);
        __builtin_amdgcn_s_setprio(1);
        mfma16<0>(acc, af, bq);
        __builtin_amdgcn_s_setprio(0);
        __builtin_amdgcn_s_barrier();

        // ---- phase 1: kh0, m-half 1 (bq reused)
#pragma unroll
        for (int i = 0; i < 4; ++i) af[i] = *(const bf16x8*)&As[bo + arow + 2048 + i * 512];
        stage_h(t + 1, 1);
        __builtin_amdgcn_s_barrier();
        asm volatile("s_waitcnt lgkmcnt(0)" ::: "memory");
        __builtin_amdgcn_sched_barrier(0);
        __builtin_amdgcn_s_setprio(1);
        mfma16<4>(acc, af, bq);
        __builtin_amdgcn_s_setprio(0);
        if (t + 1 < NT) { asm volatile("s_waitcnt vmcnt(4)" ::: "memory"); }  // this tile's kh1 landed
        else            { asm volatile("s_waitcnt vmcnt(0)" ::: "memory"); }
        __builtin_amdgcn_s_barrier();

        // ---- phase 2: kh1, m-half 0
#pragma unroll
        for (int i = 0; i < 4; ++i) af[i] = *(const bf16x8*)&As[bo + 8192 + arow + i * 512];
#pragma unroll
        for (int n = 0; n < 4; ++n) bq[n] = *(const bf16x8*)&Bs[bo + 8192 + brow + n * 512];
        stage_h(t + 1, 2);
        __builtin_amdgcn_s_barrier();
        asm volatile("s_waitcnt lgkmcnt(0)" ::: "memory");
        __builtin_amdgcn_sched_barrier(0);
        __builtin_amdgcn_s_setprio(1);
        mfma16<0>(acc, af, bq);
        __builtin_amdgcn_s_setprio(0);
        __builtin_amdgcn_s_barrier();

        // ---- phase 3: kh1, m-half 1
#pragma unroll
        for (int i = 0; i < 4; ++i) af[i] = *(const bf16x8*)&As[bo + 8192 + arow + 2048 + i * 512];
        stage_h(t + 1, 3);
        __builtin_amdgcn_s_barrier();
        asm volatile("s_waitcnt lgkmcnt(0)" ::: "memory");
        __builtin_amdgcn_sched_barrier(0);
        __builtin_amdgcn_s_setprio(1);
        mfma16<4>(acc, af, bq);
        __builtin_amdgcn_s_setprio(0);
        if (t + 1 < NT) { asm volatile("s_waitcnt vmcnt(4)" ::: "memory"); }  // next tile's kh0 landed
        __builtin_amdgcn_s_barrier();
    }

    // D layout (m89-verified): col = l16, row = quad*4 + reg
    if (EPI == 2) {
        // featG = elu(v) row-major; qT/fT = [bh][dk][s] transposed (4 s-contig
        // values per acc group -> one 8B store each).
#pragma unroll
        for (int m = 0; m < 8; ++m) {
            const int rowb = row0 + wm * 128 + m * 16 + quad * 4;
            const int bb   = rowb >> 13;          // batch (8192 rows each)
            const int s    = rowb & 8191;
#pragma unroll
            for (int n = 0; n < 4; ++n) {
                const int col = col0 + wn * 64 + n * 16 + l16;  // 0..1023
                const int h = col >> 7, dk = col & 127;
                const size_t tbase = (((size_t)(bb * 8 + h) * 128 + dk) << 13) + s;
                bf16x4 qv, fv;
#pragma unroll
                for (int r = 0; r < 4; ++r) {
                    const float v = acc[m][n][r];
                    const float f = elu1f(v);
                    C[(size_t)(rowb + r) * N + col] = (__bf16)f;   // featG
                    qv[r] = (__bf16)v;
                    fv[r] = (__bf16)f;
                }
                *(bf16x4*)(qTp + tbase) = qv;
                *(bf16x4*)(fTp + tbase) = fv;
            }
        }
    } else {
#pragma unroll
        for (int m = 0; m < 8; ++m) {
            const int rowb = row0 + wm * 128 + m * 16 + quad * 4;
#pragma unroll
            for (int n = 0; n < 4; ++n) {
                const int col = col0 + wn * 64 + n * 16 + l16;
#pragma unroll
                for (int r = 0; r < 4; ++r) {
                    float v = acc[m][n][r];
                    if (EPI == 1) v = v > 0.0f ? v : 0.0f;
                    C[(size_t)(rowb + r) * N + col] = (__bf16)v;
                }
            }
        }
    }
    (void)M;
}

// ---------------------------------------------------------------------------
__global__ __launch_bounds__(256) void cvt_f2b(const float* __restrict__ in,
                                               __bf16* __restrict__ out) {
    const size_t i = ((size_t)blockIdx.x * 256 + threadIdx.x) * 8;
    f32x4 a = *(const f32x4*)(in + i);
    f32x4 b = *(const f32x4*)(in + i + 4);
    bf16x8 o;
#pragma unroll
    for (int j = 0; j < 4; ++j) { o[j] = (__bf16)a[j]; o[4 + j] = (__bf16)b[j]; }
    *(bf16x8*)(out + i) = o;
}

// ---------------------------------------------------------------------------
__global__ __launch_bounds__(256) void transpose_f2b(const float* __restrict__ in,
                                                     __bf16* __restrict__ out,
                                                     int R, int Ccols) {
    __shared__ __bf16 tile[32][33];
    const int bc = blockIdx.x * 32;
    const int br = blockIdx.y * 32;
    const int tx = threadIdx.x & 31;
    const int ty = threadIdx.x >> 5;
#pragma unroll
    for (int i = ty; i < 32; i += 8)
        tile[i][tx] = (__bf16)in[(size_t)(br + i) * Ccols + bc + tx];
    __syncthreads();
#pragma unroll
    for (int i = ty; i < 32; i += 8)
        out[(size_t)(bc + i) * R + br + tx] = tile[tx][i];
}

// ---------------------------------------------------------------------------
// KV partials via MFMA. Per (bh, ch): KVpart[dk][dv] = sum over kSCH s of
// fT[dk][s]*qT[dv][s] (A=fT, Bt=qT, k=s). Ksum partials folded in (wn==0).
// ---------------------------------------------------------------------------
__global__ __launch_bounds__(256) void kv_gemm(const __bf16* __restrict__ fT,
                                               const __bf16* __restrict__ qT,
                                               float* __restrict__ KVpart,
                                               float* __restrict__ Kspart) {
    __shared__ __bf16 As[2][128 * 32];
    __shared__ __bf16 Bs[2][128 * 32];
    const int tid  = threadIdx.x;
    const int wave = tid >> 6, lane = tid & 63;
    const int quad = lane >> 4, l16 = lane & 15;
    const int wm = wave & 1, wn = wave >> 1;
    const int bh = blockIdx.x, ch = blockIdx.y;

    f32x4 acc[4][4] = {};
    float ksacc[4] = {};

    const int srow = lane >> 2;
    const int sk8  = ((lane & 3) - (srow >> 1)) & 3;
    const size_t base = (size_t)bh * (128 * 8192) + ch * kSCH + sk8 * 8;
    const __bf16* Ag0 = fT + base + (size_t)(wave * 32 + srow) * 8192;
    const __bf16* Bg0 = qT + base + (size_t)(wave * 32 + srow) * 8192;
    const size_t r16 = (size_t)16 * 8192;
    const int ldsw = wave * 1024;
    const int fp = ((quad + (l16 >> 1)) & 3) * 8;
    const int frow = l16 * 32 + fp;
    const int nk = kSCH / 32;
    {
        async_cp16(&As[0][ldsw], Ag0);
        async_cp16(&As[0][ldsw + 512], Ag0 + r16);
        async_cp16(&Bs[0][ldsw], Bg0);
        async_cp16(&Bs[0][ldsw + 512], Bg0 + r16);
    }
    for (int k = 0; k < nk; ++k) {
        __syncthreads();
        if (k + 1 < nk) {
            const int nb = (k + 1) & 1;
            const int ko = (k + 1) << 5;
            async_cp16(&As[nb][ldsw], Ag0 + ko);
            async_cp16(&As[nb][ldsw + 512], Ag0 + r16 + ko);
            async_cp16(&Bs[nb][ldsw], Bg0 + ko);
            async_cp16(&Bs[nb][ldsw + 512], Bg0 + r16 + ko);
        }
        const __bf16* Asb = As[k & 1];
        const __bf16* Bsb = Bs[k & 1];
        bf16x8 af[4], bfr[4];
#pragma unroll
        for (int i = 0; i < 4; ++i)
            af[i] = *(const bf16x8*)&Asb[(wm * 4 + i) * 512 + frow];
#pragma unroll
        for (int j = 0; j < 4; ++j)
            bfr[j] = *(const bf16x8*)&Bsb[(wn * 4 + j) * 512 + frow];
        if (wn == 0) {
#pragma unroll
            for (int i = 0; i < 4; ++i)
#pragma unroll
                for (int j = 0; j < 8; ++j) ksacc[i] += (float)af[i][j];
        }
#pragma unroll
        for (int i = 0; i < 4; ++i)
#pragma unroll
            for (int j = 0; j < 4; ++j)
                acc[i][j] = __builtin_amdgcn_mfma_f32_16x16x32_bf16(af[i], bfr[j], acc[i][j], 0, 0, 0);
    }

    float* outp = KVpart + (((size_t)bh * kNCH + ch) << 14);
#pragma unroll
    for (int i = 0; i < 4; ++i) {
        const int rowb = wm * 64 + i * 16 + quad * 4;
#pragma unroll
        for (int j = 0; j < 4; ++j) {
            const int col = wn * 64 + j * 16 + l16;
#pragma unroll
            for (int r = 0; r < 4; ++r)
                outp[(rowb + r) * 128 + col] = acc[i][j][r];
        }
    }
    if (wn == 0) {
#pragma unroll
        for (int i = 0; i < 4; ++i) {
            float v = ksacc[i];
            v += __shfl_xor(v, 16);
            v += __shfl_xor(v, 32);
            if (quad == 0)
                Kspart[((size_t)bh * kNCH + ch) * 128 + wm * 64 + i * 16 + l16] = v;
        }
    }
}

// ---------------------------------------------------------------------------
// merged reduce: blocks [0,1024) reduce KVpart -> bf16 KVbT (transposed
// [bh][dv][dk]); blocks [1024,1032) reduce Kspart -> fp32 Ksum.
// ---------------------------------------------------------------------------
__global__ __launch_bounds__(256) void reduce_kv(const float* __restrict__ KVpart,
                                                 const float* __restrict__ Kspart,
                                                 __bf16* __restrict__ KVbT,
                                                 float* __restrict__ Ksum) {
    const int t = threadIdx.x;
    if (blockIdx.x < 1024) {
        const size_t o = (size_t)blockIdx.x * 256 + t;
        const size_t bh = o >> 14;
        const size_t rem = o & 16383;
        float s = 0.f;
#pragma unroll 4
        for (int ch = 0; ch < kNCH; ++ch)
            s += KVpart[((bh * kNCH + ch) << 14) + rem];
        const int dk = (int)(rem >> 7), dv = (int)(rem & 127);
        KVbT[(bh << 14) + dv * 128 + dk] = (__bf16)s;
    } else {
        const int o = (blockIdx.x - 1024) * 256 + t;
        const int bh = o >> 7;
        const int dk = o & 127;
        float s = 0.f;
#pragma unroll 4
        for (int ch = 0; ch < kNCH; ++ch)
            s += Kspart[(bh * kNCH + ch) * 128 + dk];
        Ksum[o] = s;
    }
}

// ---------------------------------------------------------------------------
// msg via MFMA, Z fused (R9). Per (bh, sblk): msg[s][dv] = Z[s] *
// sum_dk feat[s][dk]*KVbT[dv][dk], Z = 1/(feat[s].Ksum + eps) computed from
// the A-fragments: quads hold k-chunks quad*8+j, so quad-shuffle-reduce of
// af[i].Ks gives the full row dot. wn==0/quad==0 lanes publish via LDS.
// ---------------------------------------------------------------------------
__global__ __launch_bounds__(256) void msg_gemm(const __bf16* __restrict__ featG,
                                                const __bf16* __restrict__ KVbT,
                                                const float* __restrict__ Ks,
                                                __bf16* __restrict__ msg) {
    __shared__ __bf16 As[2][128 * 32];
    __shared__ __bf16 Bs[2][128 * 32];
    __shared__ float KsS[128];
    __shared__ float Zsh[128];
    const int tid  = threadIdx.x;
    const int wave = tid >> 6, lane = tid & 63;
    const int quad = lane >> 4, l16 = lane & 15;
    const int wm = wave & 1, wn = wave >> 1;
    const int bh = blockIdx.x, b = bh >> 3, h = bh & 7;
    const int row0 = blockIdx.y * 128;

    if (tid < 32)
        *(f32x4*)&KsS[tid * 4] = *(const f32x4*)(Ks + bh * 128 + tid * 4);

    f32x4 acc[4][4] = {};
    float zacc[4] = {};
    const int srow = lane >> 2;
    const int sk8  = ((lane & 3) - (srow >> 1)) & 3;
    const __bf16* Ag0 = featG + (size_t)b * 8388608 + (size_t)(row0 + wave * 32 + srow) * 1024 + h * 128 + sk8 * 8;
    const __bf16* Bg0 = KVbT + ((size_t)bh << 14) + (wave * 32 + srow) * 128 + sk8 * 8;
    const size_t rA16 = (size_t)16 * 1024;
    const size_t rB16 = (size_t)16 * 128;
    const int ldsw = wave * 1024;
    const int fp = ((quad + (l16 >> 1)) & 3) * 8;
    const int frow = l16 * 32 + fp;
    const int nk = 4;
    {
        async_cp16(&As[0][ldsw], Ag0);
        async_cp16(&As[0][ldsw + 512], Ag0 + rA16);
        async_cp16(&Bs[0][ldsw], Bg0);
        async_cp16(&Bs[0][ldsw + 512], Bg0 + rB16);
    }
    for (int k = 0; k < nk; ++k) {
        __syncthreads();
        if (k + 1 < nk) {
            const int nb = (k + 1) & 1;
            const int ko = (k + 1) << 5;
            async_cp16(&As[nb][ldsw], Ag0 + ko);
            async_cp16(&As[nb][ldsw + 512], Ag0 + rA16 + ko);
            async_cp16(&Bs[nb][ldsw], Bg0 + ko);
            async_cp16(&Bs[nb][ldsw + 512], Bg0 + rB16 + ko);
        }
        const __bf16* Asb = As[k & 1];
        const __bf16* Bsb = Bs[k & 1];
        bf16x8 af[4], bfr[4];
#pragma unroll
        for (int i = 0; i < 4; ++i)
            af[i] = *(const bf16x8*)&Asb[(wm * 4 + i) * 512 + frow];
#pragma unroll
        for (int j = 0; j < 4; ++j)
            bfr[j] = *(const bf16x8*)&Bsb[(wn * 4 + j) * 512 + frow];
        // Z partial: global k of af[i][j] is k*32 + quad*8 + j
        {
            f32x4 k0 = *(const f32x4*)&KsS[k * 32 + quad * 8];
            f32x4 k1 = *(const f32x4*)&KsS[k * 32 + quad * 8 + 4];
#pragma unroll
            for (int i = 0; i < 4; ++i) {
#pragma unroll
                for (int j = 0; j < 4; ++j) {
                    zacc[i] += (float)af[i][j] * k0[j];
                    zacc[i] += (float)af[i][4 + j] * k1[j];
                }
            }
        }
#pragma unroll
        for (int i = 0; i < 4; ++i)
#pragma unroll
            for (int j = 0; j < 4; ++j)
                acc[i][j] = __builtin_amdgcn_mfma_f32_16x16x32_bf16(af[i], bfr[j], acc[i][j], 0, 0, 0);
    }

    // reduce Z over quads (k-chunks) and publish rows wm*64 + i*16 + l16
#pragma unroll
    for (int i = 0; i < 4; ++i) {
        float v = zacc[i];
        v += __shfl_xor(v, 16);
        v += __shfl_xor(v, 32);
        if (wn == 0 && quad == 0)
            Zsh[wm * 64 + i * 16 + l16] = 1.0f / (v + 1e-6f);
    }
    __syncthreads();

    const size_t obase = (size_t)b * 8388608 + (size_t)h * 128;
#pragma unroll
    for (int i = 0; i < 4; ++i) {
        const int lr0 = wm * 64 + i * 16 + quad * 4;
#pragma unroll
        for (int j = 0; j < 4; ++j) {
            const int col = wn * 64 + j * 16 + l16;
#pragma unroll
            for (int r = 0; r < 4; ++r) {
                const float v = acc[i][j][r] * Zsh[lr0 + r];
                msg[obase + (size_t)(row0 + lr0 + r) * 1024 + col] = (__bf16)v;
            }
        }
    }
}

// ---------------------------------------------------------------------------
// out = base + layernorm(y)*g + b. One WAVE per 1024-row.
// ---------------------------------------------------------------------------
template <int BF16BASE>
__global__ __launch_bounds__(256) void ln_res(const void* __restrict__ basep,
                                              const __bf16* __restrict__ y,
                                              const float* __restrict__ g,
                                              const float* __restrict__ bvec,
                                              float* __restrict__ out) {
    const int wave = threadIdx.x >> 6, lane = threadIdx.x & 63;
    const int row = blockIdx.x * 4 + wave;
    const size_t ro = (size_t)row * kD + lane * 16;
    bf16x8 y0 = *(const bf16x8*)(y + ro);
    bf16x8 y1 = *(const bf16x8*)(y + ro + 8);
    float v[16];
    float s = 0.f, sq = 0.f;
#pragma unroll
    for (int j = 0; j < 8; ++j) { v[j] = (float)y0[j]; v[8 + j] = (float)y1[j]; }
#pragma unroll
    for (int j = 0; j < 16; ++j) { s += v[j]; sq += v[j] * v[j]; }
#pragma unroll
    for (int m = 1; m < 64; m <<= 1) { s += __shfl_xor(s, m); sq += __shfl_xor(sq, m); }
    const float mu = s * (1.0f / 1024.0f);
    float var = sq * (1.0f / 1024.0f) - mu * mu;
    if (var < 0.f) var = 0.f;
    const float rstd = rsqrtf(var + 1e-5f);
    const int go = lane * 16;
    float bs[16];
    if (BF16BASE) {
        bf16x8 b0 = *(const bf16x8*)((const __bf16*)basep + ro);
        bf16x8 b1 = *(const bf16x8*)((const __bf16*)basep + ro + 8);
#pragma unroll
        for (int j = 0; j < 8; ++j) { bs[j] = (float)b0[j]; bs[8 + j] = (float)b1[j]; }
    } else {
#pragma unroll
        for (int j = 0; j < 4; ++j) {
            f32x4 bb = *(const f32x4*)((const float*)basep + ro + j * 4);
#pragma unroll
            for (int r = 0; r < 4; ++r) bs[j * 4 + r] = bb[r];
        }
    }
#pragma unroll
    for (int j = 0; j < 4; ++j) {
        f32x4 gg = *(const f32x4*)(g + go + j * 4);
        f32x4 be = *(const f32x4*)(bvec + go + j * 4);
        f32x4 o;
#pragma unroll
        for (int r = 0; r < 4; ++r)
            o[r] = bs[j * 4 + r] + (v[j * 4 + r] - mu) * rstd * gg[r] + be[r];
        *(f32x4*)(out + ro + j * 4) = o;
    }
}

// ---------------------------------------------------------------------------
extern "C" void kernel_launch(void* const* d_in, const int* in_sizes, int n_in,
                              void* d_out, int out_size, void* d_ws, size_t ws_size,
                              hipStream_t stream) {
    const float* x  = (const float*)d_in[0];
    const float* Wq = (const float*)d_in[1];
    const float* Wm = (const float*)d_in[2];
    const float* W1 = (const float*)d_in[3];
    const float* W2 = (const float*)d_in[4];
    const float* g1 = (const float*)d_in[5];
    const float* b1 = (const float*)d_in[6];
    const float* g2 = (const float*)d_in[7];
    const float* b2 = (const float*)d_in[8];
    float* out = (float*)d_out;

    const size_t BLD = (size_t)kM * kD;  // 16,777,216
    __bf16* q    = (__bf16*)d_ws;        // featG; reused as msg2
    __bf16* msg  = q + BLD;              // fT during kv; then msg; then mlp
    __bf16* hbuf = msg + BLD;            // 2*BLD (xb first half, qT second half)
    __bf16* WqT  = hbuf + 2 * BLD;       // 1M
    __bf16* WmT  = WqT + 1048576;        // 1M
    __bf16* W1T  = WmT + 1048576;        // 2M
    __bf16* W2T  = W1T + 2097152;        // 2M
    __bf16* KVb  = W2T + 2097152;        // 262144 bf16 (stored transposed)
    float* KVpart = (float*)(KVb + 262144);                // kNCH*16*16384 f32
    float* Kspart = KVpart + (size_t)kNCH * 16 * 16384;    // 16*kNCH*128
    float* Ksum   = Kspart + (size_t)16 * kNCH * 128;      // 2048
    const size_t need = ((char*)(Ksum + 2048)) - (char*)d_ws;
    if (ws_size < need) return;

    __bf16* xb   = hbuf;        // x in bf16; consumed by ln1 before W1-gemm
    __bf16* qT   = hbuf + BLD;  // written by Wq-gemm epi; dead after kv_gemm
    __bf16* fT   = msg;         // written by Wq-gemm epi; dead after kv_gemm
    __bf16* featG = q;          // elu(q) row-major, written by Wq-gemm epi
    __bf16* msg2 = q;           // featG dead after msg_gemm
    __bf16* mlp  = msg;         // msg dead after msg@Wm gemm

    const dim3 blk(256);
    const dim3 blk5(512);

    cvt_f2b<<<dim3((unsigned)(BLD / 2048)), blk, 0, stream>>>(x, xb);
    transpose_f2b<<<dim3(32, 32), blk, 0, stream>>>(Wq, WqT, kD, kD);
    transpose_f2b<<<dim3(32, 32), blk, 0, stream>>>(Wm, WmT, kD, kD);
    transpose_f2b<<<dim3(64, 32), blk, 0, stream>>>(W1, W1T, kD, 2048);
    transpose_f2b<<<dim3(32, 64), blk, 0, stream>>>(W2, W2T, 2048, kD);

    // featG/qT/fT = f(x @ Wq), fused epilogue
    gemm256<2><<<dim3(kM / 256, kD / 256), blk5, 0, stream>>>(xb, WqT, featG, qT, fT, kM, kD, kD);
    // KV partials + Ksum partials via MFMA
    kv_gemm<<<dim3(16, kNCH), blk, 0, stream>>>(fT, qT, KVpart, Kspart);
    reduce_kv<<<dim3(1032), blk, 0, stream>>>(KVpart, Kspart, KVb, Ksum);
    // msg = Z * (feat @ KV), Z fused
    msg_gemm<<<dim3(16, kL / 128), blk, 0, stream>>>(featG, KVb, Ksum, msg);
    // msg2 = msg @ Wm
    gemm256<0><<<dim3(kM / 256, kD / 256), blk5, 0, stream>>>(msg, WmT, msg2, nullptr, nullptr, kM, kD, kD);
    // x1 = x + LN(msg2) -> d_out
    ln_res<1><<<dim3(kM / 4), blk, 0, stream>>>(xb, msg2, g1, b1, out);
    // h = relu(msg2 @ W1)
    gemm256<1><<<dim3(kM / 256, 2048 / 256), blk5, 0, stream>>>(msg2, W1T, hbuf, nullptr, nullptr, kM, 2048, kD);
    // mlp = h @ W2
    gemm256<0><<<dim3(kM / 256, kD / 256), blk5, 0, stream>>>(hbuf, W2T, mlp, nullptr, nullptr, kM, kD, 2048);
    // out = x1 + LN(mlp)
    ln_res<0><<<dim3(kM / 4), blk, 0, stream>>>(out, mlp, g2, b2, out);
    (void)in_sizes; (void)n_in; (void)out_size;
}

// Round 4
// 468.678 us; speedup vs baseline: 1.0578x; 1.0578x over previous
//
#include <hip/hip_runtime.h>
#include <hip/hip_bf16.h>
#include <stdint.h>

#define AS1 __attribute__((address_space(1)))
#define AS3 __attribute__((address_space(3)))

typedef __bf16 bf16x8 __attribute__((ext_vector_type(8)));
typedef __bf16 bf16x2 __attribute__((ext_vector_type(2)));
typedef float  f32x4  __attribute__((ext_vector_type(4)));

static constexpr int kL   = 8192;
static constexpr int kD   = 1024;
static constexpr int kM   = 2 * kL;         // 16384 token rows
static constexpr int kNCH = 16;             // KV k-split chunks over L
static constexpr int kSCH = kL / kNCH;      // 512 s-rows per chunk

__device__ __forceinline__ void async_cp16(__bf16* lds, const __bf16* g) {
    __builtin_amdgcn_global_load_lds((AS1 uint32_t*)g, (AS3 uint32_t*)lds, 16, 0, 0);
}

__device__ __forceinline__ float elu1f(float x) {
    return x > 0.0f ? x + 1.0f : __expf(x);
}

template <int M0>
__device__ __forceinline__ void mfma16(f32x4 (&acc)[8][4], const bf16x8 (&af)[4],
                                       const bf16x8 (&bq)[4]) {
#pragma unroll
    for (int i = 0; i < 4; ++i)
#pragma unroll
        for (int n = 0; n < 4; ++n)
            acc[M0 + i][n] = __builtin_amdgcn_mfma_f32_16x16x32_bf16(af[i], bq[n], acc[M0 + i][n], 0, 0, 0);
}

// ---------------------------------------------------------------------------
// 256x256 8-phase GEMM (T2+T3+T4+T5). C = A @ Bt^T. R1/R2-verified m201
// schedule: prologue stages 7 half-tiles; one half-tile staged per phase;
// single counted vmcnt(6) per K-tile (3 half-tiles in flight, never 0 in
// steady state). R3's two-vmcnt(4) variant was slower — reverted.
// ---------------------------------------------------------------------------
template <int EPI>
__global__ __launch_bounds__(512, 2) void gemm256(const __bf16* __restrict__ A,
                                                  const __bf16* __restrict__ Bt,
                                                  __bf16* __restrict__ C,
                                                  int M, int N, int K) {
    __shared__ __bf16 As[32768];
    __shared__ __bf16 Bs[32768];
    const int tid  = threadIdx.x;
    const int w    = tid >> 6;
    const int l    = tid & 63;
    const int quad = l >> 4;
    const int l16  = l & 15;
    const int wm   = w >> 2;               // 0..1
    const int wn   = w & 3;                // 0..3
    const int row0 = blockIdx.x * 256;
    const int col0 = blockIdx.y * 256;

    const int srow = l >> 2;               // 0..15
    const int sc   = ((l & 3) - (srow >> 1)) & 3;
    const __bf16* Ag0 = A  + (size_t)(row0 + w * 32 + srow) * K + sc * 8;
    const __bf16* Bg0 = Bt + (size_t)(col0 + w * 32 + srow) * K + sc * 8;
    const size_t r16K = (size_t)16 * K;
    const int NT = K >> 6;

    const int fpos = ((quad + (l16 >> 1)) & 3) * 8;
    const int arow = wm * 4096 + l16 * 32 + fpos;
    const int brow = wn * 2048 + l16 * 32 + fpos;

    f32x4 acc[8][4] = {};

    auto stage_h = [&](int ts, int hh) {
        if (ts >= NT) return;
        const int off = (ts & 1) * 16384 + (hh >> 1) * 8192 + w * 1024;
        const int ko  = ts * 64 + (hh >> 1) * 32;
        if ((hh & 1) == 0) {
            async_cp16(&As[off], Ag0 + ko);
            async_cp16(&As[off + 512], Ag0 + ko + r16K);
        } else {
            async_cp16(&Bs[off], Bg0 + ko);
            async_cp16(&Bs[off + 512], Bg0 + ko + r16K);
        }
    };

    stage_h(0, 0); stage_h(0, 1); stage_h(0, 2); stage_h(0, 3);
    asm volatile("s_waitcnt vmcnt(4)" ::: "memory");
    stage_h(1, 0); stage_h(1, 1); stage_h(1, 2);
    asm volatile("s_waitcnt vmcnt(6)" ::: "memory");
    __builtin_amdgcn_s_barrier();

    for (int t = 0; t < NT; ++t) {
        const int bo = (t & 1) * 16384;
        bf16x8 af[4], bq[4];

#pragma unroll
        for (int i = 0; i < 4; ++i) af[i] = *(const bf16x8*)&As[bo + arow + i * 512];
#pragma unroll
        for (int n = 0; n < 4; ++n) bq[n] = *(const bf16x8*)&Bs[bo + brow + n * 512];
        stage_h(t + 1, 3);
        __builtin_amdgcn_s_barrier();
        asm volatile("s_waitcnt lgkmcnt(0)" ::: "memory");
        __builtin_amdgcn_sched_barrier(0);
        __builtin_amdgcn_s_setprio(1);
        mfma16<0>(acc, af, bq);
        __builtin_amdgcn_s_setprio(0);
        __builtin_amdgcn_s_barrier();

#pragma unroll
        for (int i = 0; i < 4; ++i) af[i] = *(const bf16x8*)&As[bo + arow + 2048 + i * 512];
        stage_h(t + 2, 0);
        __builtin_amdgcn_s_barrier();
        asm volatile("s_waitcnt lgkmcnt(0)" ::: "memory");
        __builtin_amdgcn_sched_barrier(0);
        __builtin_amdgcn_s_setprio(1);
        mfma16<4>(acc, af, bq);
        __builtin_amdgcn_s_setprio(0);
        __builtin_amdgcn_s_barrier();

#pragma unroll
        for (int i = 0; i < 4; ++i) af[i] = *(const bf16x8*)&As[bo + 8192 + arow + i * 512];
#pragma unroll
        for (int n = 0; n < 4; ++n) bq[n] = *(const bf16x8*)&Bs[bo + 8192 + brow + n * 512];
        stage_h(t + 2, 1);
        __builtin_amdgcn_s_barrier();
        asm volatile("s_waitcnt lgkmcnt(0)" ::: "memory");
        __builtin_amdgcn_sched_barrier(0);
        __builtin_amdgcn_s_setprio(1);
        mfma16<0>(acc, af, bq);
        __builtin_amdgcn_s_setprio(0);
        __builtin_amdgcn_s_barrier();

#pragma unroll
        for (int i = 0; i < 4; ++i) af[i] = *(const bf16x8*)&As[bo + 8192 + arow + 2048 + i * 512];
        stage_h(t + 2, 2);
        __builtin_amdgcn_s_barrier();
        asm volatile("s_waitcnt lgkmcnt(0)" ::: "memory");
        __builtin_amdgcn_sched_barrier(0);
        __builtin_amdgcn_s_setprio(1);
        mfma16<4>(acc, af, bq);
        __builtin_amdgcn_s_setprio(0);
        if (t + 2 < NT)       { asm volatile("s_waitcnt vmcnt(6)" ::: "memory"); }
        else if (t + 2 == NT) { asm volatile("s_waitcnt vmcnt(0)" ::: "memory"); }
        __builtin_amdgcn_s_barrier();
    }

    // D layout (m89-verified): col = l16, row = quad*4 + reg
#pragma unroll
    for (int m = 0; m < 8; ++m) {
        const int rowb = row0 + wm * 128 + m * 16 + quad * 4;
#pragma unroll
        for (int n = 0; n < 4; ++n) {
            const int col = col0 + wn * 64 + n * 16 + l16;
#pragma unroll
            for (int r = 0; r < 4; ++r) {
                float v = acc[m][n][r];
                if (EPI == 1) v = v > 0.0f ? v : 0.0f;
                C[(size_t)(rowb + r) * N + col] = (__bf16)v;
            }
        }
    }
    (void)M;
}

// ---------------------------------------------------------------------------
__global__ __launch_bounds__(256) void cvt_f2b(const float* __restrict__ in,
                                               __bf16* __restrict__ out) {
    const size_t i = ((size_t)blockIdx.x * 256 + threadIdx.x) * 8;
    f32x4 a = *(const f32x4*)(in + i);
    f32x4 b = *(const f32x4*)(in + i + 4);
    bf16x8 o;
#pragma unroll
    for (int j = 0; j < 4; ++j) { o[j] = (__bf16)a[j]; o[4 + j] = (__bf16)b[j]; }
    *(bf16x8*)(out + i) = o;
}

// ---------------------------------------------------------------------------
__global__ __launch_bounds__(256) void transpose_f2b(const float* __restrict__ in,
                                                     __bf16* __restrict__ out,
                                                     int R, int Ccols) {
    __shared__ __bf16 tile[32][33];
    const int bc = blockIdx.x * 32;
    const int br = blockIdx.y * 32;
    const int tx = threadIdx.x & 31;
    const int ty = threadIdx.x >> 5;
#pragma unroll
    for (int i = ty; i < 32; i += 8)
        tile[i][tx] = (__bf16)in[(size_t)(br + i) * Ccols + bc + tx];
    __syncthreads();
#pragma unroll
    for (int i = ty; i < 32; i += 8)
        out[(size_t)(bc + i) * R + br + tx] = tile[tx][i];
}

// ---------------------------------------------------------------------------
// R2-verified: per (b,h): q [s][128] -> qT [128][s] and fT = elu-transposed;
// feat written IN PLACE over q ("featG"). Coalesced LDS-tiled transpose
// (the R3 GEMM-epilogue fusion scattered 8B stores and was 2x slower).
// ---------------------------------------------------------------------------
__global__ __launch_bounds__(256) void transpose_q(__bf16* __restrict__ q_io,
                                                   __bf16* __restrict__ qT,
                                                   __bf16* __restrict__ fT) {
    __shared__ __bf16 qs[64 * 130];
    __shared__ __bf16 fs[64 * 130];
    const int bh = blockIdx.x, b = bh >> 3, h = bh & 7;
    const int s0 = blockIdx.y * 64;
    const int t = threadIdx.x;
    const size_t rowbase = (size_t)b * 8388608 + (size_t)h * 128;

#pragma unroll
    for (int c = 0; c < 4; ++c) {
        const int id = c * 256 + t;
        const int r = id >> 4, col = (id & 15) * 8;
        __bf16* gp = q_io + rowbase + (size_t)(s0 + r) * 1024 + col;
        bf16x8 qv = *(const bf16x8*)gp;
        bf16x8 fv;
#pragma unroll
        for (int j = 0; j < 8; ++j) fv[j] = (__bf16)elu1f((float)qv[j]);
        *(bf16x8*)gp = fv;                       // featG in place over q
        const int lb = r * 130 + col;
#pragma unroll
        for (int p = 0; p < 4; ++p) {
            bf16x2 qp = { qv[2 * p], qv[2 * p + 1] };
            bf16x2 fp_ = { fv[2 * p], fv[2 * p + 1] };
            *(bf16x2*)&qs[lb + 2 * p] = qp;
            *(bf16x2*)&fs[lb + 2 * p] = fp_;
        }
    }
    __syncthreads();

    const size_t ob = (size_t)bh * (128 * 8192) + s0;
#pragma unroll
    for (int c = 0; c < 4; ++c) {
        const int id = c * 256 + t;
        const int dk = id >> 3, sch = id & 7;
        bf16x8 ov, fo;
#pragma unroll
        for (int j = 0; j < 8; ++j) {
            ov[j] = qs[(sch * 8 + j) * 130 + dk];
            fo[j] = fs[(sch * 8 + j) * 130 + dk];
        }
        *(bf16x8*)(qT + ob + (size_t)dk * 8192 + sch * 8) = ov;
        *(bf16x8*)(fT + ob + (size_t)dk * 8192 + sch * 8) = fo;
    }
}

// ---------------------------------------------------------------------------
// KV partials via MFMA. Per (bh, ch): KVpart[dk][dv] = sum over kSCH s of
// fT[dk][s]*qT[dv][s] (A=fT, Bt=qT, k=s). Ksum partials folded in (wn==0).
// ---------------------------------------------------------------------------
__global__ __launch_bounds__(256) void kv_gemm(const __bf16* __restrict__ fT,
                                               const __bf16* __restrict__ qT,
                                               float* __restrict__ KVpart,
                                               float* __restrict__ Kspart) {
    __shared__ __bf16 As[2][128 * 32];
    __shared__ __bf16 Bs[2][128 * 32];
    const int tid  = threadIdx.x;
    const int wave = tid >> 6, lane = tid & 63;
    const int quad = lane >> 4, l16 = lane & 15;
    const int wm = wave & 1, wn = wave >> 1;
    const int bh = blockIdx.x, ch = blockIdx.y;

    f32x4 acc[4][4] = {};
    float ksacc[4] = {};

    const int srow = lane >> 2;
    const int sk8  = ((lane & 3) - (srow >> 1)) & 3;
    const size_t base = (size_t)bh * (128 * 8192) + ch * kSCH + sk8 * 8;
    const __bf16* Ag0 = fT + base + (size_t)(wave * 32 + srow) * 8192;
    const __bf16* Bg0 = qT + base + (size_t)(wave * 32 + srow) * 8192;
    const size_t r16 = (size_t)16 * 8192;
    const int ldsw = wave * 1024;
    const int fp = ((quad + (l16 >> 1)) & 3) * 8;
    const int frow = l16 * 32 + fp;
    const int nk = kSCH / 32;
    {
        async_cp16(&As[0][ldsw], Ag0);
        async_cp16(&As[0][ldsw + 512], Ag0 + r16);
        async_cp16(&Bs[0][ldsw], Bg0);
        async_cp16(&Bs[0][ldsw + 512], Bg0 + r16);
    }
    for (int k = 0; k < nk; ++k) {
        __syncthreads();
        if (k + 1 < nk) {
            const int nb = (k + 1) & 1;
            const int ko = (k + 1) << 5;
            async_cp16(&As[nb][ldsw], Ag0 + ko);
            async_cp16(&As[nb][ldsw + 512], Ag0 + r16 + ko);
            async_cp16(&Bs[nb][ldsw], Bg0 + ko);
            async_cp16(&Bs[nb][ldsw + 512], Bg0 + r16 + ko);
        }
        const __bf16* Asb = As[k & 1];
        const __bf16* Bsb = Bs[k & 1];
        bf16x8 af[4], bfr[4];
#pragma unroll
        for (int i = 0; i < 4; ++i)
            af[i] = *(const bf16x8*)&Asb[(wm * 4 + i) * 512 + frow];
#pragma unroll
        for (int j = 0; j < 4; ++j)
            bfr[j] = *(const bf16x8*)&Bsb[(wn * 4 + j) * 512 + frow];
        if (wn == 0) {
#pragma unroll
            for (int i = 0; i < 4; ++i)
#pragma unroll
                for (int j = 0; j < 8; ++j) ksacc[i] += (float)af[i][j];
        }
#pragma unroll
        for (int i = 0; i < 4; ++i)
#pragma unroll
            for (int j = 0; j < 4; ++j)
                acc[i][j] = __builtin_amdgcn_mfma_f32_16x16x32_bf16(af[i], bfr[j], acc[i][j], 0, 0, 0);
    }

    float* outp = KVpart + (((size_t)bh * kNCH + ch) << 14);
#pragma unroll
    for (int i = 0; i < 4; ++i) {
        const int rowb = wm * 64 + i * 16 + quad * 4;
#pragma unroll
        for (int j = 0; j < 4; ++j) {
            const int col = wn * 64 + j * 16 + l16;
#pragma unroll
            for (int r = 0; r < 4; ++r)
                outp[(rowb + r) * 128 + col] = acc[i][j][r];
        }
    }
    if (wn == 0) {
#pragma unroll
        for (int i = 0; i < 4; ++i) {
            float v = ksacc[i];
            v += __shfl_xor(v, 16);
            v += __shfl_xor(v, 32);
            if (quad == 0)
                Kspart[((size_t)bh * kNCH + ch) * 128 + wm * 64 + i * 16 + l16] = v;
        }
    }
}

// ---------------------------------------------------------------------------
// merged reduce: blocks [0,1024) reduce KVpart -> bf16 KVbT (transposed
// [bh][dv][dk]); blocks [1024,1032) reduce Kspart -> fp32 Ksum.
// ---------------------------------------------------------------------------
__global__ __launch_bounds__(256) void reduce_kv(const float* __restrict__ KVpart,
                                                 const float* __restrict__ Kspart,
                                                 __bf16* __restrict__ KVbT,
                                                 float* __restrict__ Ksum) {
    const int t = threadIdx.x;
    if (blockIdx.x < 1024) {
        const size_t o = (size_t)blockIdx.x * 256 + t;
        const size_t bh = o >> 14;
        const size_t rem = o & 16383;
        float s = 0.f;
#pragma unroll 4
        for (int ch = 0; ch < kNCH; ++ch)
            s += KVpart[((bh * kNCH + ch) << 14) + rem];
        const int dk = (int)(rem >> 7), dv = (int)(rem & 127);
        KVbT[(bh << 14) + dv * 128 + dk] = (__bf16)s;
    } else {
        const int o = (blockIdx.x - 1024) * 256 + t;
        const int bh = o >> 7;
        const int dk = o & 127;
        float s = 0.f;
#pragma unroll 4
        for (int ch = 0; ch < kNCH; ++ch)
            s += Kspart[(bh * kNCH + ch) * 128 + dk];
        Ksum[o] = s;
    }
}

// ---------------------------------------------------------------------------
// msg via MFMA, Z fused (R3-verified). Per (bh, sblk): msg[s][dv] = Z[s] *
// sum_dk feat[s][dk]*KVbT[dv][dk]; Z = 1/(feat[s].Ksum + eps) computed from
// the A-fragments (quads hold k-chunks, quad-shuffle reduce).
// ---------------------------------------------------------------------------
__global__ __launch_bounds__(256) void msg_gemm(const __bf16* __restrict__ featG,
                                                const __bf16* __restrict__ KVbT,
                                                const float* __restrict__ Ks,
                                                __bf16* __restrict__ msg) {
    __shared__ __bf16 As[2][128 * 32];
    __shared__ __bf16 Bs[2][128 * 32];
    __shared__ float KsS[128];
    __shared__ float Zsh[128];
    const int tid  = threadIdx.x;
    const int wave = tid >> 6, lane = tid & 63;
    const int quad = lane >> 4, l16 = lane & 15;
    const int wm = wave & 1, wn = wave >> 1;
    const int bh = blockIdx.x, b = bh >> 3, h = bh & 7;
    const int row0 = blockIdx.y * 128;

    if (tid < 32)
        *(f32x4*)&KsS[tid * 4] = *(const f32x4*)(Ks + bh * 128 + tid * 4);

    f32x4 acc[4][4] = {};
    float zacc[4] = {};
    const int srow = lane >> 2;
    const int sk8  = ((lane & 3) - (srow >> 1)) & 3;
    const __bf16* Ag0 = featG + (size_t)b * 8388608 + (size_t)(row0 + wave * 32 + srow) * 1024 + h * 128 + sk8 * 8;
    const __bf16* Bg0 = KVbT + ((size_t)bh << 14) + (wave * 32 + srow) * 128 + sk8 * 8;
    const size_t rA16 = (size_t)16 * 1024;
    const size_t rB16 = (size_t)16 * 128;
    const int ldsw = wave * 1024;
    const int fp = ((quad + (l16 >> 1)) & 3) * 8;
    const int frow = l16 * 32 + fp;
    const int nk = 4;
    {
        async_cp16(&As[0][ldsw], Ag0);
        async_cp16(&As[0][ldsw + 512], Ag0 + rA16);
        async_cp16(&Bs[0][ldsw], Bg0);
        async_cp16(&Bs[0][ldsw + 512], Bg0 + rB16);
    }
    for (int k = 0; k < nk; ++k) {
        __syncthreads();
        if (k + 1 < nk) {
            const int nb = (k + 1) & 1;
            const int ko = (k + 1) << 5;
            async_cp16(&As[nb][ldsw], Ag0 + ko);
            async_cp16(&As[nb][ldsw + 512], Ag0 + rA16 + ko);
            async_cp16(&Bs[nb][ldsw], Bg0 + ko);
            async_cp16(&Bs[nb][ldsw + 512], Bg0 + rB16 + ko);
        }
        const __bf16* Asb = As[k & 1];
        const __bf16* Bsb = Bs[k & 1];
        bf16x8 af[4], bfr[4];
#pragma unroll
        for (int i = 0; i < 4; ++i)
            af[i] = *(const bf16x8*)&Asb[(wm * 4 + i) * 512 + frow];
#pragma unroll
        for (int j = 0; j < 4; ++j)
            bfr[j] = *(const bf16x8*)&Bsb[(wn * 4 + j) * 512 + frow];
        // Z partial: global k of af[i][j] is k*32 + quad*8 + j
        {
            f32x4 k0 = *(const f32x4*)&KsS[k * 32 + quad * 8];
            f32x4 k1 = *(const f32x4*)&KsS[k * 32 + quad * 8 + 4];
#pragma unroll
            for (int i = 0; i < 4; ++i) {
#pragma unroll
                for (int j = 0; j < 4; ++j) {
                    zacc[i] += (float)af[i][j] * k0[j];
                    zacc[i] += (float)af[i][4 + j] * k1[j];
                }
            }
        }
#pragma unroll
        for (int i = 0; i < 4; ++i)
#pragma unroll
            for (int j = 0; j < 4; ++j)
                acc[i][j] = __builtin_amdgcn_mfma_f32_16x16x32_bf16(af[i], bfr[j], acc[i][j], 0, 0, 0);
    }

    // reduce Z over quads (k-chunks), publish rows wm*64 + i*16 + l16
#pragma unroll
    for (int i = 0; i < 4; ++i) {
        float v = zacc[i];
        v += __shfl_xor(v, 16);
        v += __shfl_xor(v, 32);
        if (wn == 0 && quad == 0)
            Zsh[wm * 64 + i * 16 + l16] = 1.0f / (v + 1e-6f);
    }
    __syncthreads();

    const size_t obase = (size_t)b * 8388608 + (size_t)h * 128;
#pragma unroll
    for (int i = 0; i < 4; ++i) {
        const int lr0 = wm * 64 + i * 16 + quad * 4;
#pragma unroll
        for (int j = 0; j < 4; ++j) {
            const int col = wn * 64 + j * 16 + l16;
#pragma unroll
            for (int r = 0; r < 4; ++r) {
                const float v = acc[i][j][r] * Zsh[lr0 + r];
                msg[obase + (size_t)(row0 + lr0 + r) * 1024 + col] = (__bf16)v;
            }
        }
    }
}

// ---------------------------------------------------------------------------
// out = base + layernorm(y)*g + b. One WAVE per 1024-row.
// ---------------------------------------------------------------------------
template <int BF16BASE>
__global__ __launch_bounds__(256) void ln_res(const void* __restrict__ basep,
                                              const __bf16* __restrict__ y,
                                              const float* __restrict__ g,
                                              const float* __restrict__ bvec,
                                              float* __restrict__ out) {
    const int wave = threadIdx.x >> 6, lane = threadIdx.x & 63;
    const int row = blockIdx.x * 4 + wave;
    const size_t ro = (size_t)row * kD + lane * 16;
    bf16x8 y0 = *(const bf16x8*)(y + ro);
    bf16x8 y1 = *(const bf16x8*)(y + ro + 8);
    float v[16];
    float s = 0.f, sq = 0.f;
#pragma unroll
    for (int j = 0; j < 8; ++j) { v[j] = (float)y0[j]; v[8 + j] = (float)y1[j]; }
#pragma unroll
    for (int j = 0; j < 16; ++j) { s += v[j]; sq += v[j] * v[j]; }
#pragma unroll
    for (int m = 1; m < 64; m <<= 1) { s += __shfl_xor(s, m); sq += __shfl_xor(sq, m); }
    const float mu = s * (1.0f / 1024.0f);
    float var = sq * (1.0f / 1024.0f) - mu * mu;
    if (var < 0.f) var = 0.f;
    const float rstd = rsqrtf(var + 1e-5f);
    const int go = lane * 16;
    float bs[16];
    if (BF16BASE) {
        bf16x8 b0 = *(const bf16x8*)((const __bf16*)basep + ro);
        bf16x8 b1 = *(const bf16x8*)((const __bf16*)basep + ro + 8);
#pragma unroll
        for (int j = 0; j < 8; ++j) { bs[j] = (float)b0[j]; bs[8 + j] = (float)b1[j]; }
    } else {
#pragma unroll
        for (int j = 0; j < 4; ++j) {
            f32x4 bb = *(const f32x4*)((const float*)basep + ro + j * 4);
#pragma unroll
            for (int r = 0; r < 4; ++r) bs[j * 4 + r] = bb[r];
        }
    }
#pragma unroll
    for (int j = 0; j < 4; ++j) {
        f32x4 gg = *(const f32x4*)(g + go + j * 4);
        f32x4 be = *(const f32x4*)(bvec + go + j * 4);
        f32x4 o;
#pragma unroll
        for (int r = 0; r < 4; ++r)
            o[r] = bs[j * 4 + r] + (v[j * 4 + r] - mu) * rstd * gg[r] + be[r];
        *(f32x4*)(out + ro + j * 4) = o;
    }
}

// ---------------------------------------------------------------------------
extern "C" void kernel_launch(void* const* d_in, const int* in_sizes, int n_in,
                              void* d_out, int out_size, void* d_ws, size_t ws_size,
                              hipStream_t stream) {
    const float* x  = (const float*)d_in[0];
    const float* Wq = (const float*)d_in[1];
    const float* Wm = (const float*)d_in[2];
    const float* W1 = (const float*)d_in[3];
    const float* W2 = (const float*)d_in[4];
    const float* g1 = (const float*)d_in[5];
    const float* b1 = (const float*)d_in[6];
    const float* g2 = (const float*)d_in[7];
    const float* b2 = (const float*)d_in[8];
    float* out = (float*)d_out;

    const size_t BLD = (size_t)kM * kD;  // 16,777,216
    __bf16* q    = (__bf16*)d_ws;        // q -> featG in place; reused as msg2
    __bf16* msg  = q + BLD;              // fT during kv; then msg; then mlp
    __bf16* hbuf = msg + BLD;            // 2*BLD (xb first half, qT second half)
    __bf16* WqT  = hbuf + 2 * BLD;       // 1M
    __bf16* WmT  = WqT + 1048576;        // 1M
    __bf16* W1T  = WmT + 1048576;        // 2M
    __bf16* W2T  = W1T + 2097152;        // 2M
    __bf16* KVb  = W2T + 2097152;        // 262144 bf16 (stored transposed)
    float* KVpart = (float*)(KVb + 262144);                // kNCH*16*16384 f32
    float* Kspart = KVpart + (size_t)kNCH * 16 * 16384;    // 16*kNCH*128
    float* Ksum   = Kspart + (size_t)16 * kNCH * 128;      // 2048
    const size_t need = ((char*)(Ksum + 2048)) - (char*)d_ws;
    if (ws_size < need) return;

    __bf16* xb   = hbuf;        // x in bf16; consumed by ln1 before W1-gemm
    __bf16* qT   = hbuf + BLD;  // dead after kv_gemm (before W1-gemm)
    __bf16* fT   = msg;         // dead after kv_gemm (before msg_gemm writes)
    __bf16* featG = q;          // elu(q) in place after transpose_q
    __bf16* msg2 = q;           // featG dead after msg_gemm
    __bf16* mlp  = msg;         // msg dead after msg@Wm gemm

    const dim3 blk(256);
    const dim3 blk5(512);

    cvt_f2b<<<dim3((unsigned)(BLD / 2048)), blk, 0, stream>>>(x, xb);
    transpose_f2b<<<dim3(32, 32), blk, 0, stream>>>(Wq, WqT, kD, kD);
    transpose_f2b<<<dim3(32, 32), blk, 0, stream>>>(Wm, WmT, kD, kD);
    transpose_f2b<<<dim3(64, 32), blk, 0, stream>>>(W1, W1T, kD, 2048);
    transpose_f2b<<<dim3(32, 64), blk, 0, stream>>>(W2, W2T, 2048, kD);

    // q = x @ Wq
    gemm256<0><<<dim3(kM / 256, kD / 256), blk5, 0, stream>>>(xb, WqT, q, kM, kD, kD);
    // qT/fT transposes + feat in place over q
    transpose_q<<<dim3(16, 128), blk, 0, stream>>>(q, qT, fT);
    // KV partials + Ksum partials via MFMA
    kv_gemm<<<dim3(16, kNCH), blk, 0, stream>>>(fT, qT, KVpart, Kspart);
    reduce_kv<<<dim3(1032), blk, 0, stream>>>(KVpart, Kspart, KVb, Ksum);
    // msg = Z * (feat @ KV), Z fused
    msg_gemm<<<dim3(16, kL / 128), blk, 0, stream>>>(featG, KVb, Ksum, msg);
    // msg2 = msg @ Wm
    gemm256<0><<<dim3(kM / 256, kD / 256), blk5, 0, stream>>>(msg, WmT, msg2, kM, kD, kD);
    // x1 = x + LN(msg2) -> d_out
    ln_res<1><<<dim3(kM / 4), blk, 0, stream>>>(xb, msg2, g1, b1, out);
    // h = relu(msg2 @ W1)
    gemm256<1><<<dim3(kM / 256, 2048 / 256), blk5, 0, stream>>>(msg2, W1T, hbuf, kM, 2048, kD);
    // mlp = h @ W2
    gemm256<0><<<dim3(kM / 256, kD / 256), blk5, 0, stream>>>(hbuf, W2T, mlp, kM, kD, 2048);
    // out = x1 + LN(mlp)
    ln_res<0><<<dim3(kM / 4), blk, 0, stream>>>(out, mlp, g2, b2, out);
    (void)in_sizes; (void)n_in; (void)out_size;
}

// Round 5
// 448.820 us; speedup vs baseline: 1.1046x; 1.0442x over previous
//
#include <hip/hip_runtime.h>
#include <hip/hip_bf16.h>
#include <stdint.h>

#define AS1 __attribute__((address_space(1)))
#define AS3 __attribute__((address_space(3)))

typedef __bf16 bf16x8 __attribute__((ext_vector_type(8)));
typedef __bf16 bf16x2 __attribute__((ext_vector_type(2)));
typedef float  f32x4  __attribute__((ext_vector_type(4)));

static constexpr int kL   = 8192;
static constexpr int kD   = 1024;
static constexpr int kM   = 2 * kL;         // 16384 token rows
static constexpr int kNCH = 16;             // KV k-split chunks over L
static constexpr int kSCH = kL / kNCH;      // 512 s-rows per chunk

__device__ __forceinline__ void async_cp16(__bf16* lds, const __bf16* g) {
    __builtin_amdgcn_global_load_lds((AS1 uint32_t*)g, (AS3 uint32_t*)lds, 16, 0, 0);
}

__device__ __forceinline__ float elu1f(float x) {
    return x > 0.0f ? x + 1.0f : __expf(x);
}

// elu applied to a bf16x8 fragment in-register; bit-identical to the old
// staged-fT path ((__bf16)elu1f((float)v) per element).
__device__ __forceinline__ bf16x8 elu8(bf16x8 v) {
    bf16x8 r;
#pragma unroll
    for (int j = 0; j < 8; ++j) r[j] = (__bf16)elu1f((float)v[j]);
    return r;
}

template <int M0>
__device__ __forceinline__ void mfma16(f32x4 (&acc)[8][4], const bf16x8 (&af)[4],
                                       const bf16x8 (&bq)[4]) {
#pragma unroll
    for (int i = 0; i < 4; ++i)
#pragma unroll
        for (int n = 0; n < 4; ++n)
            acc[M0 + i][n] = __builtin_amdgcn_mfma_f32_16x16x32_bf16(af[i], bq[n], acc[M0 + i][n], 0, 0, 0);
}

// ---------------------------------------------------------------------------
// 256x256 8-phase GEMM (T2+T3+T4+T5). C = A @ Bt^T. R1/R2/R4-verified m201
// schedule — DO NOT TOUCH the K-loop (R3's variant regressed).
// ---------------------------------------------------------------------------
template <int EPI>
__global__ __launch_bounds__(512, 2) void gemm256(const __bf16* __restrict__ A,
                                                  const __bf16* __restrict__ Bt,
                                                  __bf16* __restrict__ C,
                                                  int M, int N, int K) {
    __shared__ __bf16 As[32768];
    __shared__ __bf16 Bs[32768];
    const int tid  = threadIdx.x;
    const int w    = tid >> 6;
    const int l    = tid & 63;
    const int quad = l >> 4;
    const int l16  = l & 15;
    const int wm   = w >> 2;               // 0..1
    const int wn   = w & 3;                // 0..3
    const int row0 = blockIdx.x * 256;
    const int col0 = blockIdx.y * 256;

    const int srow = l >> 2;               // 0..15
    const int sc   = ((l & 3) - (srow >> 1)) & 3;
    const __bf16* Ag0 = A  + (size_t)(row0 + w * 32 + srow) * K + sc * 8;
    const __bf16* Bg0 = Bt + (size_t)(col0 + w * 32 + srow) * K + sc * 8;
    const size_t r16K = (size_t)16 * K;
    const int NT = K >> 6;

    const int fpos = ((quad + (l16 >> 1)) & 3) * 8;
    const int arow = wm * 4096 + l16 * 32 + fpos;
    const int brow = wn * 2048 + l16 * 32 + fpos;

    f32x4 acc[8][4] = {};

    auto stage_h = [&](int ts, int hh) {
        if (ts >= NT) return;
        const int off = (ts & 1) * 16384 + (hh >> 1) * 8192 + w * 1024;
        const int ko  = ts * 64 + (hh >> 1) * 32;
        if ((hh & 1) == 0) {
            async_cp16(&As[off], Ag0 + ko);
            async_cp16(&As[off + 512], Ag0 + ko + r16K);
        } else {
            async_cp16(&Bs[off], Bg0 + ko);
            async_cp16(&Bs[off + 512], Bg0 + ko + r16K);
        }
    };

    stage_h(0, 0); stage_h(0, 1); stage_h(0, 2); stage_h(0, 3);
    asm volatile("s_waitcnt vmcnt(4)" ::: "memory");
    stage_h(1, 0); stage_h(1, 1); stage_h(1, 2);
    asm volatile("s_waitcnt vmcnt(6)" ::: "memory");
    __builtin_amdgcn_s_barrier();

    for (int t = 0; t < NT; ++t) {
        const int bo = (t & 1) * 16384;
        bf16x8 af[4], bq[4];

#pragma unroll
        for (int i = 0; i < 4; ++i) af[i] = *(const bf16x8*)&As[bo + arow + i * 512];
#pragma unroll
        for (int n = 0; n < 4; ++n) bq[n] = *(const bf16x8*)&Bs[bo + brow + n * 512];
        stage_h(t + 1, 3);
        __builtin_amdgcn_s_barrier();
        asm volatile("s_waitcnt lgkmcnt(0)" ::: "memory");
        __builtin_amdgcn_sched_barrier(0);
        __builtin_amdgcn_s_setprio(1);
        mfma16<0>(acc, af, bq);
        __builtin_amdgcn_s_setprio(0);
        __builtin_amdgcn_s_barrier();

#pragma unroll
        for (int i = 0; i < 4; ++i) af[i] = *(const bf16x8*)&As[bo + arow + 2048 + i * 512];
        stage_h(t + 2, 0);
        __builtin_amdgcn_s_barrier();
        asm volatile("s_waitcnt lgkmcnt(0)" ::: "memory");
        __builtin_amdgcn_sched_barrier(0);
        __builtin_amdgcn_s_setprio(1);
        mfma16<4>(acc, af, bq);
        __builtin_amdgcn_s_setprio(0);
        __builtin_amdgcn_s_barrier();

#pragma unroll
        for (int i = 0; i < 4; ++i) af[i] = *(const bf16x8*)&As[bo + 8192 + arow + i * 512];
#pragma unroll
        for (int n = 0; n < 4; ++n) bq[n] = *(const bf16x8*)&Bs[bo + 8192 + brow + n * 512];
        stage_h(t + 2, 1);
        __builtin_amdgcn_s_barrier();
        asm volatile("s_waitcnt lgkmcnt(0)" ::: "memory");
        __builtin_amdgcn_sched_barrier(0);
        __builtin_amdgcn_s_setprio(1);
        mfma16<0>(acc, af, bq);
        __builtin_amdgcn_s_setprio(0);
        __builtin_amdgcn_s_barrier();

#pragma unroll
        for (int i = 0; i < 4; ++i) af[i] = *(const bf16x8*)&As[bo + 8192 + arow + 2048 + i * 512];
        stage_h(t + 2, 2);
        __builtin_amdgcn_s_barrier();
        asm volatile("s_waitcnt lgkmcnt(0)" ::: "memory");
        __builtin_amdgcn_sched_barrier(0);
        __builtin_amdgcn_s_setprio(1);
        mfma16<4>(acc, af, bq);
        __builtin_amdgcn_s_setprio(0);
        if (t + 2 < NT)       { asm volatile("s_waitcnt vmcnt(6)" ::: "memory"); }
        else if (t + 2 == NT) { asm volatile("s_waitcnt vmcnt(0)" ::: "memory"); }
        __builtin_amdgcn_s_barrier();
    }

    // D layout (m89-verified): col = l16, row = quad*4 + reg
#pragma unroll
    for (int m = 0; m < 8; ++m) {
        const int rowb = row0 + wm * 128 + m * 16 + quad * 4;
#pragma unroll
        for (int n = 0; n < 4; ++n) {
            const int col = col0 + wn * 64 + n * 16 + l16;
#pragma unroll
            for (int r = 0; r < 4; ++r) {
                float v = acc[m][n][r];
                if (EPI == 1) v = v > 0.0f ? v : 0.0f;
                C[(size_t)(rowb + r) * N + col] = (__bf16)v;
            }
        }
    }
    (void)M;
}

// ---------------------------------------------------------------------------
// R10: merged prep — cvt x->bf16 (blocks [0,8192)) + the 4 weight transposes
// (blocks [8192,14336)) in ONE dispatch. Saves 4 launch/tail overheads.
// ---------------------------------------------------------------------------
__device__ __forceinline__ void transpose_body(const float* __restrict__ in,
                                               __bf16* __restrict__ out,
                                               int R, int Ccols, int bx, int by,
                                               int t, __bf16 (*tile)[33]) {
    const int bc = bx * 32, br = by * 32;
    const int tx = t & 31, ty = t >> 5;
#pragma unroll
    for (int i = ty; i < 32; i += 8)
        tile[i][tx] = (__bf16)in[(size_t)(br + i) * Ccols + bc + tx];
    __syncthreads();
#pragma unroll
    for (int i = ty; i < 32; i += 8)
        out[(size_t)(bc + i) * R + br + tx] = tile[tx][i];
}

__global__ __launch_bounds__(256) void prep(const float* __restrict__ x,
                                            __bf16* __restrict__ xb,
                                            const float* __restrict__ Wq,
                                            __bf16* __restrict__ WqT,
                                            const float* __restrict__ Wm,
                                            __bf16* __restrict__ WmT,
                                            const float* __restrict__ W1,
                                            __bf16* __restrict__ W1T,
                                            const float* __restrict__ W2,
                                            __bf16* __restrict__ W2T) {
    __shared__ __bf16 tile[32][33];
    const int t = threadIdx.x;
    int id = blockIdx.x;
    if (id < 8192) {
        const size_t i = ((size_t)id * 256 + t) * 8;
        f32x4 a = *(const f32x4*)(x + i);
        f32x4 b = *(const f32x4*)(x + i + 4);
        bf16x8 o;
#pragma unroll
        for (int j = 0; j < 4; ++j) { o[j] = (__bf16)a[j]; o[4 + j] = (__bf16)b[j]; }
        *(bf16x8*)(xb + i) = o;
        return;
    }
    id -= 8192;
    if (id < 1024) {
        transpose_body(Wq, WqT, 1024, 1024, id & 31, id >> 5, t, tile);
    } else if (id < 2048) {
        const int i2 = id - 1024;
        transpose_body(Wm, WmT, 1024, 1024, i2 & 31, i2 >> 5, t, tile);
    } else if (id < 4096) {
        const int i2 = id - 2048;
        transpose_body(W1, W1T, 1024, 2048, i2 & 63, i2 >> 6, t, tile);
    } else {
        const int i2 = id - 4096;
        transpose_body(W2, W2T, 2048, 1024, i2 & 31, i2 >> 5, t, tile);
    }
}

// ---------------------------------------------------------------------------
// R10: pure q -> qT transpose per (b,h). No fT/featG (elu is applied
// in-register by the consumers — bit-identical values, 64 MB less traffic).
// ---------------------------------------------------------------------------
__global__ __launch_bounds__(256) void transpose_q(const __bf16* __restrict__ q,
                                                   __bf16* __restrict__ qT) {
    __shared__ __bf16 qs[64 * 130];
    const int bh = blockIdx.x, b = bh >> 3, h = bh & 7;
    const int s0 = blockIdx.y * 64;
    const int t = threadIdx.x;
    const size_t rowbase = (size_t)b * 8388608 + (size_t)h * 128;

#pragma unroll
    for (int c = 0; c < 4; ++c) {
        const int id = c * 256 + t;
        const int r = id >> 4, col = (id & 15) * 8;
        bf16x8 qv = *(const bf16x8*)(q + rowbase + (size_t)(s0 + r) * 1024 + col);
        const int lb = r * 130 + col;
#pragma unroll
        for (int p = 0; p < 4; ++p) {
            bf16x2 qp = { qv[2 * p], qv[2 * p + 1] };
            *(bf16x2*)&qs[lb + 2 * p] = qp;
        }
    }
    __syncthreads();

    const size_t ob = (size_t)bh * (128 * 8192) + s0;
#pragma unroll
    for (int c = 0; c < 4; ++c) {
        const int id = c * 256 + t;
        const int dk = id >> 3, sch = id & 7;
        bf16x8 ov;
#pragma unroll
        for (int j = 0; j < 8; ++j) ov[j] = qs[(sch * 8 + j) * 130 + dk];
        *(bf16x8*)(qT + ob + (size_t)dk * 8192 + sch * 8) = ov;
    }
}

// ---------------------------------------------------------------------------
// KV partials via MFMA. A and B both come from the SAME qT tile (A rows = dk
// with elu in-register, B rows = dv raw) — single staged operand, half the
// fetch/LDS of R4. Ksum partials folded in (wn==0 waves).
// ---------------------------------------------------------------------------
__global__ __launch_bounds__(256) void kv_gemm(const __bf16* __restrict__ qT,
                                               float* __restrict__ KVpart,
                                               float* __restrict__ Kspart) {
    __shared__ __bf16 Qs[2][128 * 32];
    const int tid  = threadIdx.x;
    const int wave = tid >> 6, lane = tid & 63;
    const int quad = lane >> 4, l16 = lane & 15;
    const int wm = wave & 1, wn = wave >> 1;
    const int bh = blockIdx.x, ch = blockIdx.y;

    f32x4 acc[4][4] = {};
    float ksacc[4] = {};

    const int srow = lane >> 2;
    const int sk8  = ((lane & 3) - (srow >> 1)) & 3;
    const size_t base = (size_t)bh * (128 * 8192) + ch * kSCH + sk8 * 8;
    const __bf16* Qg0 = qT + base + (size_t)(wave * 32 + srow) * 8192;
    const size_t r16 = (size_t)16 * 8192;
    const int ldsw = wave * 1024;
    const int fp = ((quad + (l16 >> 1)) & 3) * 8;
    const int frow = l16 * 32 + fp;
    const int nk = kSCH / 32;
    {
        async_cp16(&Qs[0][ldsw], Qg0);
        async_cp16(&Qs[0][ldsw + 512], Qg0 + r16);
    }
    for (int k = 0; k < nk; ++k) {
        __syncthreads();
        if (k + 1 < nk) {
            const int nb = (k + 1) & 1;
            const int ko = (k + 1) << 5;
            async_cp16(&Qs[nb][ldsw], Qg0 + ko);
            async_cp16(&Qs[nb][ldsw + 512], Qg0 + r16 + ko);
        }
        const __bf16* Qsb = Qs[k & 1];
        bf16x8 af[4], bfr[4];
#pragma unroll
        for (int i = 0; i < 4; ++i)
            af[i] = elu8(*(const bf16x8*)&Qsb[(wm * 4 + i) * 512 + frow]);
#pragma unroll
        for (int j = 0; j < 4; ++j)
            bfr[j] = *(const bf16x8*)&Qsb[(wn * 4 + j) * 512 + frow];
        if (wn == 0) {
#pragma unroll
            for (int i = 0; i < 4; ++i)
#pragma unroll
                for (int j = 0; j < 8; ++j) ksacc[i] += (float)af[i][j];
        }
#pragma unroll
        for (int i = 0; i < 4; ++i)
#pragma unroll
            for (int j = 0; j < 4; ++j)
                acc[i][j] = __builtin_amdgcn_mfma_f32_16x16x32_bf16(af[i], bfr[j], acc[i][j], 0, 0, 0);
    }

    float* outp = KVpart + (((size_t)bh * kNCH + ch) << 14);
#pragma unroll
    for (int i = 0; i < 4; ++i) {
        const int rowb = wm * 64 + i * 16 + quad * 4;
#pragma unroll
        for (int j = 0; j < 4; ++j) {
            const int col = wn * 64 + j * 16 + l16;
#pragma unroll
            for (int r = 0; r < 4; ++r)
                outp[(rowb + r) * 128 + col] = acc[i][j][r];
        }
    }
    if (wn == 0) {
#pragma unroll
        for (int i = 0; i < 4; ++i) {
            float v = ksacc[i];
            v += __shfl_xor(v, 16);
            v += __shfl_xor(v, 32);
            if (quad == 0)
                Kspart[((size_t)bh * kNCH + ch) * 128 + wm * 64 + i * 16 + l16] = v;
        }
    }
}

// ---------------------------------------------------------------------------
// merged reduce: blocks [0,1024) reduce KVpart -> bf16 KVbT (transposed
// [bh][dv][dk]); blocks [1024,1032) reduce Kspart -> fp32 Ksum.
// ---------------------------------------------------------------------------
__global__ __launch_bounds__(256) void reduce_kv(const float* __restrict__ KVpart,
                                                 const float* __restrict__ Kspart,
                                                 __bf16* __restrict__ KVbT,
                                                 float* __restrict__ Ksum) {
    const int t = threadIdx.x;
    if (blockIdx.x < 1024) {
        const size_t o = (size_t)blockIdx.x * 256 + t;
        const size_t bh = o >> 14;
        const size_t rem = o & 16383;
        float s = 0.f;
#pragma unroll 4
        for (int ch = 0; ch < kNCH; ++ch)
            s += KVpart[((bh * kNCH + ch) << 14) + rem];
        const int dk = (int)(rem >> 7), dv = (int)(rem & 127);
        KVbT[(bh << 14) + dv * 128 + dk] = (__bf16)s;
    } else {
        const int o = (blockIdx.x - 1024) * 256 + t;
        const int bh = o >> 7;
        const int dk = o & 127;
        float s = 0.f;
#pragma unroll 4
        for (int ch = 0; ch < kNCH; ++ch)
            s += Kspart[(bh * kNCH + ch) * 128 + dk];
        Ksum[o] = s;
    }
}

// ---------------------------------------------------------------------------
// msg via MFMA, Z fused. A = RAW q (row-major); elu applied in-register to
// A-fragments (feeds both MFMA-A and the Z dot). Bt = KVbT, K=128.
// ---------------------------------------------------------------------------
__global__ __launch_bounds__(256) void msg_gemm(const __bf16* __restrict__ q,
                                                const __bf16* __restrict__ KVbT,
                                                const float* __restrict__ Ks,
                                                __bf16* __restrict__ msg) {
    __shared__ __bf16 As[2][128 * 32];
    __shared__ __bf16 Bs[2][128 * 32];
    __shared__ float KsS[128];
    __shared__ float Zsh[128];
    const int tid  = threadIdx.x;
    const int wave = tid >> 6, lane = tid & 63;
    const int quad = lane >> 4, l16 = lane & 15;
    const int wm = wave & 1, wn = wave >> 1;
    const int bh = blockIdx.x, b = bh >> 3, h = bh & 7;
    const int row0 = blockIdx.y * 128;

    if (tid < 32)
        *(f32x4*)&KsS[tid * 4] = *(const f32x4*)(Ks + bh * 128 + tid * 4);

    f32x4 acc[4][4] = {};
    float zacc[4] = {};
    const int srow = lane >> 2;
    const int sk8  = ((lane & 3) - (srow >> 1)) & 3;
    const __bf16* Ag0 = q + (size_t)b * 8388608 + (size_t)(row0 + wave * 32 + srow) * 1024 + h * 128 + sk8 * 8;
    const __bf16* Bg0 = KVbT + ((size_t)bh << 14) + (wave * 32 + srow) * 128 + sk8 * 8;
    const size_t rA16 = (size_t)16 * 1024;
    const size_t rB16 = (size_t)16 * 128;
    const int ldsw = wave * 1024;
    const int fp = ((quad + (l16 >> 1)) & 3) * 8;
    const int frow = l16 * 32 + fp;
    const int nk = 4;
    {
        async_cp16(&As[0][ldsw], Ag0);
        async_cp16(&As[0][ldsw + 512], Ag0 + rA16);
        async_cp16(&Bs[0][ldsw], Bg0);
        async_cp16(&Bs[0][ldsw + 512], Bg0 + rB16);
    }
    for (int k = 0; k < nk; ++k) {
        __syncthreads();
        if (k + 1 < nk) {
            const int nb = (k + 1) & 1;
            const int ko = (k + 1) << 5;
            async_cp16(&As[nb][ldsw], Ag0 + ko);
            async_cp16(&As[nb][ldsw + 512], Ag0 + rA16 + ko);
            async_cp16(&Bs[nb][ldsw], Bg0 + ko);
            async_cp16(&Bs[nb][ldsw + 512], Bg0 + rB16 + ko);
        }
        const __bf16* Asb = As[k & 1];
        const __bf16* Bsb = Bs[k & 1];
        bf16x8 af[4], bfr[4];
#pragma unroll
        for (int i = 0; i < 4; ++i)
            af[i] = elu8(*(const bf16x8*)&Asb[(wm * 4 + i) * 512 + frow]);
#pragma unroll
        for (int j = 0; j < 4; ++j)
            bfr[j] = *(const bf16x8*)&Bsb[(wn * 4 + j) * 512 + frow];
        // Z partial: global k of af[i][j] is k*32 + quad*8 + j
        {
            f32x4 k0 = *(const f32x4*)&KsS[k * 32 + quad * 8];
            f32x4 k1 = *(const f32x4*)&KsS[k * 32 + quad * 8 + 4];
#pragma unroll
            for (int i = 0; i < 4; ++i) {
#pragma unroll
                for (int j = 0; j < 4; ++j) {
                    zacc[i] += (float)af[i][j] * k0[j];
                    zacc[i] += (float)af[i][4 + j] * k1[j];
                }
            }
        }
#pragma unroll
        for (int i = 0; i < 4; ++i)
#pragma unroll
            for (int j = 0; j < 4; ++j)
                acc[i][j] = __builtin_amdgcn_mfma_f32_16x16x32_bf16(af[i], bfr[j], acc[i][j], 0, 0, 0);
    }

    // reduce Z over quads (k-chunks), publish rows wm*64 + i*16 + l16
#pragma unroll
    for (int i = 0; i < 4; ++i) {
        float v = zacc[i];
        v += __shfl_xor(v, 16);
        v += __shfl_xor(v, 32);
        if (wn == 0 && quad == 0)
            Zsh[wm * 64 + i * 16 + l16] = 1.0f / (v + 1e-6f);
    }
    __syncthreads();

    const size_t obase = (size_t)b * 8388608 + (size_t)h * 128;
#pragma unroll
    for (int i = 0; i < 4; ++i) {
        const int lr0 = wm * 64 + i * 16 + quad * 4;
#pragma unroll
        for (int j = 0; j < 4; ++j) {
            const int col = wn * 64 + j * 16 + l16;
#pragma unroll
            for (int r = 0; r < 4; ++r) {
                const float v = acc[i][j][r] * Zsh[lr0 + r];
                msg[obase + (size_t)(row0 + lr0 + r) * 1024 + col] = (__bf16)v;
            }
        }
    }
}

// ---------------------------------------------------------------------------
// out = base + layernorm(y)*g + b. One WAVE per 1024-row.
// ---------------------------------------------------------------------------
template <int BF16BASE>
__global__ __launch_bounds__(256) void ln_res(const void* __restrict__ basep,
                                              const __bf16* __restrict__ y,
                                              const float* __restrict__ g,
                                              const float* __restrict__ bvec,
                                              float* __restrict__ out) {
    const int wave = threadIdx.x >> 6, lane = threadIdx.x & 63;
    const int row = blockIdx.x * 4 + wave;
    const size_t ro = (size_t)row * kD + lane * 16;
    bf16x8 y0 = *(const bf16x8*)(y + ro);
    bf16x8 y1 = *(const bf16x8*)(y + ro + 8);
    float v[16];
    float s = 0.f, sq = 0.f;
#pragma unroll
    for (int j = 0; j < 8; ++j) { v[j] = (float)y0[j]; v[8 + j] = (float)y1[j]; }
#pragma unroll
    for (int j = 0; j < 16; ++j) { s += v[j]; sq += v[j] * v[j]; }
#pragma unroll
    for (int m = 1; m < 64; m <<= 1) { s += __shfl_xor(s, m); sq += __shfl_xor(sq, m); }
    const float mu = s * (1.0f / 1024.0f);
    float var = sq * (1.0f / 1024.0f) - mu * mu;
    if (var < 0.f) var = 0.f;
    const float rstd = rsqrtf(var + 1e-5f);
    const int go = lane * 16;
    float bs[16];
    if (BF16BASE) {
        bf16x8 b0 = *(const bf16x8*)((const __bf16*)basep + ro);
        bf16x8 b1 = *(const bf16x8*)((const __bf16*)basep + ro + 8);
#pragma unroll
        for (int j = 0; j < 8; ++j) { bs[j] = (float)b0[j]; bs[8 + j] = (float)b1[j]; }
    } else {
#pragma unroll
        for (int j = 0; j < 4; ++j) {
            f32x4 bb = *(const f32x4*)((const float*)basep + ro + j * 4);
#pragma unroll
            for (int r = 0; r < 4; ++r) bs[j * 4 + r] = bb[r];
        }
    }
#pragma unroll
    for (int j = 0; j < 4; ++j) {
        f32x4 gg = *(const f32x4*)(g + go + j * 4);
        f32x4 be = *(const f32x4*)(bvec + go + j * 4);
        f32x4 o;
#pragma unroll
        for (int r = 0; r < 4; ++r)
            o[r] = bs[j * 4 + r] + (v[j * 4 + r] - mu) * rstd * gg[r] + be[r];
        *(f32x4*)(out + ro + j * 4) = o;
    }
}

// ---------------------------------------------------------------------------
extern "C" void kernel_launch(void* const* d_in, const int* in_sizes, int n_in,
                              void* d_out, int out_size, void* d_ws, size_t ws_size,
                              hipStream_t stream) {
    const float* x  = (const float*)d_in[0];
    const float* Wq = (const float*)d_in[1];
    const float* Wm = (const float*)d_in[2];
    const float* W1 = (const float*)d_in[3];
    const float* W2 = (const float*)d_in[4];
    const float* g1 = (const float*)d_in[5];
    const float* b1 = (const float*)d_in[6];
    const float* g2 = (const float*)d_in[7];
    const float* b2 = (const float*)d_in[8];
    float* out = (float*)d_out;

    const size_t BLD = (size_t)kM * kD;  // 16,777,216
    __bf16* q    = (__bf16*)d_ws;        // q (raw, stays raw); reused as msg2
    __bf16* msg  = q + BLD;              // msg after msg_gemm; then mlp
    __bf16* hbuf = msg + BLD;            // 2*BLD (xb first half, qT second half)
    __bf16* WqT  = hbuf + 2 * BLD;       // 1M
    __bf16* WmT  = WqT + 1048576;        // 1M
    __bf16* W1T  = WmT + 1048576;        // 2M
    __bf16* W2T  = W1T + 2097152;        // 2M
    __bf16* KVb  = W2T + 2097152;        // 262144 bf16 (stored transposed)
    float* KVpart = (float*)(KVb + 262144);                // kNCH*16*16384 f32
    float* Kspart = KVpart + (size_t)kNCH * 16 * 16384;    // 16*kNCH*128
    float* Ksum   = Kspart + (size_t)16 * kNCH * 128;      // 2048
    const size_t need = ((char*)(Ksum + 2048)) - (char*)d_ws;
    if (ws_size < need) return;

    __bf16* xb   = hbuf;        // x in bf16; consumed by ln1 before W1-gemm
    __bf16* qT   = hbuf + BLD;  // dead after kv_gemm (before W1-gemm)
    __bf16* msg2 = q;           // q dead after msg_gemm
    __bf16* mlp  = msg;         // msg dead after msg@Wm gemm

    const dim3 blk(256);
    const dim3 blk5(512);

    // prep: cvt x->xb + 4 weight transposes, one dispatch
    prep<<<dim3(14336), blk, 0, stream>>>(x, xb, Wq, WqT, Wm, WmT, W1, W1T, W2, W2T);

    // q = x @ Wq
    gemm256<0><<<dim3(kM / 256, kD / 256), blk5, 0, stream>>>(xb, WqT, q, kM, kD, kD);
    // qT transpose (elu applied in-register downstream)
    transpose_q<<<dim3(16, 128), blk, 0, stream>>>(q, qT);
    // KV partials + Ksum partials via MFMA (single shared operand tile)
    kv_gemm<<<dim3(16, kNCH), blk, 0, stream>>>(qT, KVpart, Kspart);
    reduce_kv<<<dim3(1032), blk, 0, stream>>>(KVpart, Kspart, KVb, Ksum);
    // msg = Z * (elu(q) @ KV), Z fused
    msg_gemm<<<dim3(16, kL / 128), blk, 0, stream>>>(q, KVb, Ksum, msg);
    // msg2 = msg @ Wm
    gemm256<0><<<dim3(kM / 256, kD / 256), blk5, 0, stream>>>(msg, WmT, msg2, kM, kD, kD);
    // x1 = x + LN(msg2) -> d_out
    ln_res<1><<<dim3(kM / 4), blk, 0, stream>>>(xb, msg2, g1, b1, out);
    // h = relu(msg2 @ W1)
    gemm256<1><<<dim3(kM / 256, 2048 / 256), blk5, 0, stream>>>(msg2, W1T, hbuf, kM, 2048, kD);
    // mlp = h @ W2
    gemm256<0><<<dim3(kM / 256, kD / 256), blk5, 0, stream>>>(hbuf, W2T, mlp, kM, kD, 2048);
    // out = x1 + LN(mlp)
    ln_res<0><<<dim3(kM / 4), blk, 0, stream>>>(out, mlp, g2, b2, out);
    (void)in_sizes; (void)n_in; (void)out_size;
}